// Round 7
// baseline (180.390 us; speedup 1.0000x reference)
//
#include <hip/hip_runtime.h>
#include <stdint.h>

#define NQ   8192
#define NB   2
#define KNN  10
#define K1   11                 // top-11 incl. self (dist 0 = global min key); dropped at end
#define NTOT (NB * NQ)
#define IDXMASK 0x1FFFu

#define NW    16                // waves per block (1024 threads); block owns 64 queries
#define NHALF 2                 // candidate set split across 2 blocks per query-group
#define HCAND (NQ / NHALF)      // 4096 candidates per block
#define CPW   (HCAND / NW)      // 256 candidates per wave
#define TILE  64                // candidates broadcast per load tile
#define NTILE (CPW / TILE)      // 4
#define CAP   18                // collect capacity per (query, wave) cell; lambda ~5.5
#define NSUB  32                // subsample points per wave (stride 8) -> 512 per half

// LDS word index, lane-major: 2-way bank aliasing only (free)
#define CK(s, c, lane) (((s) * NW + (c)) * 64 + (lane))

static __device__ __forceinline__ uint32_t umin32(uint32_t a, uint32_t b) { return a < b ? a : b; }
static __device__ __forceinline__ uint32_t umax32(uint32_t a, uint32_t b) { return a > b ? a : b; }
static __device__ __forceinline__ float rdlane(float v, int t) {
    return __uint_as_float(__builtin_amdgcn_readlane(__float_as_uint(v), t));
}

static __device__ __forceinline__ void insert11(uint32_t (&l)[K1], uint32_t key) {
#pragma unroll
    for (int s = 0; s < K1; ++s) {
        const uint32_t m = l[s];
        l[s] = umin32(key, m);
        key  = umax32(key, m);
    }
}

// One block = 64 queries (lane = query) x half the candidate set (16 waves split it).
// Candidates are lane-loaded (coalesced) then broadcast to all lanes via v_readlane.
// Phase 1: subsample top-11 -> tau (>= true 11th key). Phase 2: branch-free
// key-space filter collect. Phase 3: tree-merge -> half-exact top-11 -> partial.
__global__ __launch_bounds__(1024, 8) void plap_knn_partial(
    const float* __restrict__ p1, uint32_t* __restrict__ part)
{
    __shared__ uint32_t ckeys[CAP * NW * 64];   // 73728 B
    __shared__ uint32_t scnt[NW * 64];          // 4096 B
    __shared__ uint32_t stau[64];               // 256 B -> 78080 B (2 blocks/CU)

    const int lane  = threadIdx.x & 63;
    const int wave  = threadIdx.x >> 6;
    const int wq    = __builtin_amdgcn_readfirstlane(wave);
    const int group = blockIdx.x >> 1;          // 0..255
    const int half  = blockIdx.x & 1;
    const int b     = group >> 7;
    const int qi    = ((group & 127) << 6) | lane;   // query index in batch
    const int qidG  = group * 64 + lane;             // global query id

    const float* __restrict__ P = p1 + (size_t)b * NQ * 3;
    const float qx = P[qi * 3 + 0];
    const float qy = P[qi * 3 + 1];
    const float qz = P[qi * 3 + 2];

    const int j0 = half * HCAND + wq * CPW;     // wave's candidate range base (uniform)

    // ---------------- phase 1: subsample top-11 -> tau ----------------
    {
        uint32_t l[K1];
#pragma unroll
        for (int s = 0; s < K1; ++s) l[s] = 0xFFFFFFFFu;

        // lane li loads sample (li & 31): idx = j0 + (li&31)*8
        const int sidx = j0 + (lane & (NSUB - 1)) * (CPW / NSUB);
        const float sx = P[sidx * 3 + 0];
        const float sy = P[sidx * 3 + 1];
        const float sz = P[sidx * 3 + 2];
#pragma unroll
        for (int t = 0; t < NSUB; ++t) {
            const float cx = rdlane(sx, t), cy = rdlane(sy, t), cz = rdlane(sz, t);
            const float dx = qx - cx, dy = qy - cy, dz = qz - cz;
            const float d  = fmaf(dx, dx, fmaf(dy, dy, dz * dz));
            insert11(l, (__float_as_uint(d) & ~IDXMASK) | (uint32_t)(j0 + t * (CPW / NSUB)));
        }
#pragma unroll
        for (int s = 0; s < K1; ++s) ckeys[CK(s, wq, lane)] = l[s];
    }
    __syncthreads();

    for (int st = 1; st < NW; st <<= 1) {       // tree-merge -> 11th of 512 sample
        if ((wq & (2 * st - 1)) == 0) {
            uint32_t A[K1];
#pragma unroll
            for (int s = 0; s < K1; ++s) A[s] = ckeys[CK(s, wq, lane)];
#pragma unroll
            for (int e = 0; e < K1; ++e) insert11(A, ckeys[CK(e, wq + st, lane)]);
            if (2 * st < NW) {
#pragma unroll
                for (int s = 0; s < K1; ++s) ckeys[CK(s, wq, lane)] = A[s];
            } else {
                stau[lane] = A[K1 - 1];
            }
        }
        __syncthreads();
    }
    const uint32_t tau = stau[lane];

    // ---------------- phase 2: lane-broadcast filter + collect ----------------
    {
        uint32_t cnt = 0;
        uint32_t* const cell = &ckeys[wq * 64 + lane];      // stride NW*64 words per slot

        int idx = (j0 + lane) * 3;
        float cx = P[idx + 0], cy = P[idx + 1], cz = P[idx + 2];
        for (int tile = 0; tile < NTILE; ++tile) {          // dynamic: keeps code small
            const int nidx = (j0 + umin32(tile + 1, NTILE - 1) * TILE + lane) * 3;
            const float nx = P[nidx + 0], ny = P[nidx + 1], nz = P[nidx + 2];
            const int jt = j0 + tile * TILE;
#pragma unroll
            for (int t = 0; t < TILE; ++t) {
                const float bx = rdlane(cx, t), by = rdlane(cy, t), bz = rdlane(cz, t);
                const float dx = qx - bx, dy = qy - by, dz = qz - bz;
                const float d  = fmaf(dx, dx, fmaf(dy, dy, dz * dz));
                const uint32_t key = (__float_as_uint(d) & ~IDXMASK) | (uint32_t)(jt + t);
                cell[umin32(cnt, CAP - 1) * (NW * 64)] = key;   // unconditional store
                cnt += (key <= tau) ? 1u : 0u;                  // key-space: exact superset
            }
            cx = nx; cy = ny; cz = nz;
        }

        if (__any(cnt >= CAP)) {
            // exact fallback for this wave (rare): full insert-chain redo
            uint32_t L[K1];
#pragma unroll
            for (int s = 0; s < K1; ++s) L[s] = 0xFFFFFFFFu;
            const float* __restrict__ cp = P + (size_t)j0 * 3;
            int jj = j0;
            for (int t = 0; t < CPW; ++t) {
                const float ax = cp[0], ay = cp[1], az = cp[2];
                cp += 3;
                const float dx = qx - ax, dy = qy - ay, dz = qz - az;
                const float d  = fmaf(dx, dx, fmaf(dy, dy, dz * dz));
                insert11(L, (__float_as_uint(d) & ~IDXMASK) | (uint32_t)jj);
                ++jj;
            }
#pragma unroll
            for (int s = 0; s < K1; ++s) ckeys[CK(s, wq, lane)] = L[s];
            cnt = K1;
        }
        scnt[wq * 64 + lane] = cnt;
    }
    __syncthreads();

    // ---------------- phase 3: tree-merge cells -> half-exact top-11 ----------------
    uint32_t F[K1];
#pragma unroll
    for (int s = 0; s < K1; ++s) F[s] = 0xFFFFFFFFu;

    for (int st = 1; st < NW; st <<= 1) {
        if ((wq & (2 * st - 1)) == 0) {
            if (st == 1) {
                const uint32_t ca = scnt[wq * 64 + lane];
                for (uint32_t e = 0; e < ca; ++e) insert11(F, ckeys[CK(e, wq, lane)]);
                const uint32_t cb = scnt[(wq + 1) * 64 + lane];
                for (uint32_t e = 0; e < cb; ++e) insert11(F, ckeys[CK(e, wq + 1, lane)]);
            } else {
#pragma unroll
                for (int e = 0; e < K1; ++e) insert11(F, ckeys[CK(e, wq + st, lane)]);
            }
        }
        __syncthreads();
        if ((wq & (2 * st - 1)) == 0 && 2 * st < NW) {
#pragma unroll
            for (int s = 0; s < K1; ++s) ckeys[CK(s, wq, lane)] = F[s];
        }
        __syncthreads();
    }

    if (wq == 0) {
#pragma unroll
        for (int s = 0; s < K1; ++s)
            part[((size_t)half * K1 + s) * NTOT + qidG] = F[s];
    }
}

// Merge the two half-partials per query -> exact top-11 -> Laplacian L1 loss.
__global__ __launch_bounds__(256) void plap_merge_loss(
    const float* __restrict__ p1, const float* __restrict__ p2,
    const uint32_t* __restrict__ part, float* __restrict__ out)
{
    const int qid = blockIdx.x * 256 + threadIdx.x;   // 0..NTOT-1
    const int b   = qid >> 13;
    const int qi  = qid & (NQ - 1);
    const float* __restrict__ P1 = p1 + (size_t)b * NQ * 3;
    const float* __restrict__ P2 = p2 + (size_t)b * NQ * 3;

    uint32_t F[K1];
#pragma unroll
    for (int s = 0; s < K1; ++s) F[s] = part[(size_t)s * NTOT + qid];
#pragma unroll
    for (int s = 0; s < K1; ++s) insert11(F, part[((size_t)K1 + s) * NTOT + qid]);

    float s1x = 0.f, s1y = 0.f, s1z = 0.f, s2x = 0.f, s2y = 0.f, s2z = 0.f;
#pragma unroll
    for (int s = 1; s < K1; ++s) {                    // F[0] = self (d = 0)
        const int n = (int)(F[s] & IDXMASK);
        s1x += P1[n * 3 + 0]; s1y += P1[n * 3 + 1]; s1z += P1[n * 3 + 2];
        s2x += P2[n * 3 + 0]; s2y += P2[n * 3 + 1]; s2z += P2[n * 3 + 2];
    }
    const float invk = 1.0f / (float)KNN;
    const float lx = (s1x * invk - P1[qi * 3 + 0]) - (s2x * invk - P2[qi * 3 + 0]);
    const float ly = (s1y * invk - P1[qi * 3 + 1]) - (s2y * invk - P2[qi * 3 + 1]);
    const float lz = (s1z * invk - P1[qi * 3 + 2]) - (s2z * invk - P2[qi * 3 + 2]);
    float acc = fabsf(lx) + fabsf(ly) + fabsf(lz);

#pragma unroll
    for (int off = 32; off > 0; off >>= 1)
        acc += __shfl_down(acc, off, 64);
    if ((threadIdx.x & 63) == 0)
        atomicAdd(out, acc * (1.0f / (float)(NTOT * 3)));
}

extern "C" void kernel_launch(void* const* d_in, const int* in_sizes, int n_in,
                              void* d_out, int out_size, void* d_ws, size_t ws_size,
                              hipStream_t stream) {
    const float* p1 = (const float*)d_in[0];
    const float* p2 = (const float*)d_in[1];
    float* out      = (float*)d_out;
    uint32_t* part  = (uint32_t*)d_ws;   // 2 * 11 * 16384 * 4 B = 1.44 MB

    hipMemsetAsync(d_out, 0, sizeof(float), stream);
    plap_knn_partial<<<dim3(NTOT / 64 * NHALF), dim3(NW * 64), 0, stream>>>(p1, part);
    plap_merge_loss<<<dim3(NTOT / 256), dim3(256), 0, stream>>>(p1, p2, part, out);
}